// Round 8
// baseline (604.596 us; speedup 1.0000x reference)
//
#include <hip/hip_runtime.h>
#include <hip/hip_bf16.h>

// GATv2 x3 layers, MI355X. f32 in/out; edge_index int32.
// R8: fused per-dst kernel with TWO waves per node (split edge list halves,
// exact online-softmax state merge via LDS). Self-loop peeled into half-A
// init. Unroll-2 hot loop, int32 addressing, no score buffers.

#define NN 10000    // nodes
#define NE 200000   // edges
#define ND 128      // node dim (layer 0 input)
#define ED 16       // edge dim
#define CD 64       // conv dim (per head)
#define NH 5        // heads
#define HC 320      // NH*CD
#define NEG 0.2f

// ---- CSR build: count ----
__global__ void k_count(const int* __restrict__ dst, int* __restrict__ deg) {
  int e = blockIdx.x * blockDim.x + threadIdx.x;
  if (e >= NE) return;
  atomicAdd(&deg[dst[e]], 1);
}

// ---- CSR build: exclusive scan (single block) ----
__global__ __launch_bounds__(256) void k_scan(const int* __restrict__ deg,
                                              int* __restrict__ rowptr) {
  __shared__ int part[256];
  int t = threadIdx.x;
  int base = t * 40;
  int local[40];
  int s = 0;
  #pragma unroll
  for (int j = 0; j < 40; j++) {
    int i = base + j;
    local[j] = (i < NN) ? deg[i] : 0;
    s += local[j];
  }
  part[t] = s;
  __syncthreads();
  for (int off = 1; off < 256; off <<= 1) {
    int v = (t >= off) ? part[t - off] : 0;
    __syncthreads();
    part[t] += v;
    __syncthreads();
  }
  int prefix = (t > 0) ? part[t - 1] : 0;
  #pragma unroll
  for (int j = 0; j < 40; j++) {
    int i = base + j;
    if (i < NN) rowptr[i] = prefix;
    prefix += local[j];
  }
  if (t == 255) rowptr[NN] = prefix;
}

// ---- CSR build: fill ----
__global__ void k_fill(const int* __restrict__ ei, const int* __restrict__ rowptr,
                       int* __restrict__ cursor, int* __restrict__ csr_eid,
                       int* __restrict__ csr_src) {
  int e = blockIdx.x * blockDim.x + threadIdx.x;
  if (e >= NE) return;
  int d = ei[NE + e];
  int slot = atomicAdd(&cursor[d], 1);
  int pos = rowptr[d] + slot;
  csr_eid[pos] = e;
  csr_src[pos] = ei[e];
}

// ---- loop_attr = mean of incoming edge_attr (gather, wave per node) ----
__global__ __launch_bounds__(256) void k_loopattr(const int* __restrict__ csr_eid,
                                                  const int* __restrict__ rowptr,
                                                  const float* __restrict__ eattr,
                                                  float* __restrict__ loop_attr) {
  int wave = threadIdx.x >> 6, lane = threadIdx.x & 63;
  int d = blockIdx.x * 4 + wave;
  if (d >= NN) return;
  int g = lane >> 4, k = lane & 15;
  int b = rowptr[d], n = rowptr[d + 1] - b;
  float s = 0.f;
  for (int i = g; i < n; i += 4)
    s += eattr[(size_t)csr_eid[b + i] * ED + k];
  s += __shfl_xor(s, 16, 64);
  s += __shfl_xor(s, 32, 64);
  if (g == 0) loop_attr[d * ED + k] = s / fmaxf((float)n, 1.0f);
}

// ---- ea_csr[p] = edge attrs permuted into CSR order (real edges only) ----
__global__ void k_eacsr(const int* __restrict__ csr_eid, const float* __restrict__ eattr,
                        float* __restrict__ ea_csr) {
  int idx = blockIdx.x * blockDim.x + threadIdx.x;  // (p, quad)
  if (idx >= NE * 4) return;
  int p = idx >> 2, q = idx & 3;
  const float4* sp = (const float4*)(eattr + (size_t)csr_eid[p] * ED);
  ((float4*)(ea_csr + (size_t)p * ED))[q] = sp[q];
}

// ---- xl = h @ Wl + bl  (no LDS; h rows via uniform broadcast loads) ----
template <int D>
__global__ __launch_bounds__(320) void k_xl(const float* __restrict__ h,
                                            const float* __restrict__ Wl,
                                            const float* __restrict__ bl,
                                            float* __restrict__ xl) {
  constexpr int NPB = 8;
  int node0 = blockIdx.x * NPB;
  int t = threadIdx.x;  // output column 0..319
  float acc[NPB];
  #pragma unroll
  for (int i = 0; i < NPB; i++) acc[i] = 0.f;
  for (int k = 0; k < D; k += 4) {
    float w0 = Wl[(k + 0) * HC + t];
    float w1 = Wl[(k + 1) * HC + t];
    float w2 = Wl[(k + 2) * HC + t];
    float w3 = Wl[(k + 3) * HC + t];
    #pragma unroll
    for (int i = 0; i < NPB; i++) {
      float4 hv = *(const float4*)(h + (size_t)(node0 + i) * D + k);
      acc[i] += hv.x * w0 + hv.y * w1 + hv.z * w2 + hv.w * w3;
    }
  }
  float bv = bl[t];
  #pragma unroll
  for (int i = 0; i < NPB; i++)
    xl[(size_t)(node0 + i) * HC + t] = acc[i] + bv;
}

// score for one edge: v_c = leakyrelu(xs+xd+ea.We); sc_h = v*att (pre-reduce)
#define SCORE1(E0, E1, E2, E3, XS, SC)                                        \
  _Pragma("unroll")                                                           \
  for (int h = 0; h < NH; h++) {                                              \
    float v = XS[h] + xd[h];                                                  \
    v += E0.x * Wr[0][h]  + E0.y * Wr[1][h]  + E0.z * Wr[2][h]  + E0.w * Wr[3][h];  \
    v += E1.x * Wr[4][h]  + E1.y * Wr[5][h]  + E1.z * Wr[6][h]  + E1.w * Wr[7][h];  \
    v += E2.x * Wr[8][h]  + E2.y * Wr[9][h]  + E2.z * Wr[10][h] + E2.w * Wr[11][h]; \
    v += E3.x * Wr[12][h] + E3.y * Wr[13][h] + E3.z * Wr[14][h] + E3.w * Wr[15][h]; \
    v *= (v > 0.f) ? 1.0f : NEG;                                              \
    SC[h] = v * attv[h];                                                      \
  }

// ---- fused GATv2: 2 waves per dst node (edge-list halves), LDS merge ----
__global__ __launch_bounds__(256) void k_fused(
    const int* __restrict__ csr_src, const int* __restrict__ rowptr,
    const float* __restrict__ ea_csr, const float* __restrict__ loop_attr,
    const float* __restrict__ xl, const float* __restrict__ We,
    const float* __restrict__ att, const float* __restrict__ bias,
    float* __restrict__ out) {
  __shared__ float s_acc[2][NH][CD];
  __shared__ float s_ml[2][NH][2];

  int w = threadIdx.x >> 6, lane = threadIdx.x & 63;
  int node_slot = w >> 1;          // 0..1 within block
  int half = w & 1;                // 0 = A (self-loop + merge), 1 = B
  int d = blockIdx.x * 2 + node_slot;

  const float* xlL = xl + lane;

  float Wr[ED][NH];
  #pragma unroll
  for (int k = 0; k < ED; k++)
    #pragma unroll
    for (int h = 0; h < NH; h++)
      Wr[k][h] = We[k * HC + h * CD + lane];
  float attv[NH];
  #pragma unroll
  for (int h = 0; h < NH; h++) attv[h] = att[h * CD + lane];

  int bd = d * HC;
  float xd[NH];
  #pragma unroll
  for (int h = 0; h < NH; h++) xd[h] = xlL[bd + h * CD];

  int r0 = rowptr[d], r1 = rowptr[d + 1];
  int n = r1 - r0;
  int mid = r0 + (n >> 1);
  int p0, p1;
  float m[NH], l[NH], acc[NH];

  if (half == 0) {
    // peel self loop: exact init
    const float4* lap = (const float4*)(loop_attr + d * ED);
    float4 a0 = lap[0], a1 = lap[1], a2 = lap[2], a3 = lap[3];
    float scS[NH];
    SCORE1(a0, a1, a2, a3, xd, scS);
    #pragma unroll
    for (int off = 1; off < 64; off <<= 1) {
      #pragma unroll
      for (int h = 0; h < NH; h++) scS[h] += __shfl_xor(scS[h], off, 64);
    }
    #pragma unroll
    for (int h = 0; h < NH; h++) { m[h] = scS[h]; l[h] = 1.f; acc[h] = xd[h]; }
    p0 = r0; p1 = mid;
  } else {
    #pragma unroll
    for (int h = 0; h < NH; h++) { m[h] = -1e30f; l[h] = 0.f; acc[h] = 0.f; }
    p0 = mid; p1 = r1;
  }

  int p = p0;
  for (; p + 2 <= p1; p += 2) {
    int s0 = csr_src[p], s1 = csr_src[p + 1];
    const float4* q = (const float4*)ea_csr + p * 4;
    float4 e00 = q[0], e01 = q[1], e02 = q[2], e03 = q[3];
    float4 e10 = q[4], e11 = q[5], e12 = q[6], e13 = q[7];
    int b0 = s0 * HC, b1 = s1 * HC;
    float xs0[NH], xs1[NH];
    #pragma unroll
    for (int h = 0; h < NH; h++) { xs0[h] = xlL[b0 + h * CD]; xs1[h] = xlL[b1 + h * CD]; }

    float sc0[NH], sc1[NH];
    SCORE1(e00, e01, e02, e03, xs0, sc0);
    SCORE1(e10, e11, e12, e13, xs1, sc1);
    #pragma unroll
    for (int off = 1; off < 64; off <<= 1) {
      #pragma unroll
      for (int h = 0; h < NH; h++) {
        sc0[h] += __shfl_xor(sc0[h], off, 64);
        sc1[h] += __shfl_xor(sc1[h], off, 64);
      }
    }
    #pragma unroll
    for (int h = 0; h < NH; h++) {
      float mn = fmaxf(m[h], fmaxf(sc0[h], sc1[h]));
      float r  = __expf(m[h] - mn);
      float g0 = __expf(sc0[h] - mn);
      float g1 = __expf(sc1[h] - mn);
      l[h]   = l[h] * r + g0 + g1;
      acc[h] = acc[h] * r + g0 * xs0[h] + g1 * xs1[h];
      m[h] = mn;
    }
  }
  if (p < p1) {  // odd tail
    int s0 = csr_src[p];
    const float4* q = (const float4*)ea_csr + p * 4;
    float4 e00 = q[0], e01 = q[1], e02 = q[2], e03 = q[3];
    int b0 = s0 * HC;
    float xs0[NH];
    #pragma unroll
    for (int h = 0; h < NH; h++) xs0[h] = xlL[b0 + h * CD];
    float sc0[NH];
    SCORE1(e00, e01, e02, e03, xs0, sc0);
    #pragma unroll
    for (int off = 1; off < 64; off <<= 1) {
      #pragma unroll
      for (int h = 0; h < NH; h++) sc0[h] += __shfl_xor(sc0[h], off, 64);
    }
    #pragma unroll
    for (int h = 0; h < NH; h++) {
      float mn = fmaxf(m[h], sc0[h]);
      float r  = __expf(m[h] - mn);
      float g0 = __expf(sc0[h] - mn);
      l[h]   = l[h] * r + g0;
      acc[h] = acc[h] * r + g0 * xs0[h];
      m[h] = mn;
    }
  }

  // merge half-B state into half-A via LDS (exact)
  if (half == 1) {
    #pragma unroll
    for (int h = 0; h < NH; h++) {
      s_acc[node_slot][h][lane] = acc[h];
      if (lane == 0) { s_ml[node_slot][h][0] = m[h]; s_ml[node_slot][h][1] = l[h]; }
    }
  }
  __syncthreads();
  if (half == 0) {
    float v = 0.f;
    #pragma unroll
    for (int h = 0; h < NH; h++) {
      float mB = s_ml[node_slot][h][0];
      float lB = s_ml[node_slot][h][1];
      float aB = s_acc[node_slot][h][lane];
      float ms = fmaxf(m[h], mB);
      float rA = __expf(m[h] - ms);
      float rB = __expf(mB - ms);
      v += (acc[h] * rA + aB * rB) / (l[h] * rA + lB * rB);
    }
    v = v * (1.0f / NH) + bias[lane];
    v = v > 0.f ? v : expm1f(v);
    out[d * CD + lane] = v;
  }
}

extern "C" void kernel_launch(void* const* d_in, const int* in_sizes, int n_in,
                              void* d_out, int out_size, void* d_ws, size_t ws_size,
                              hipStream_t stream) {
  const float* x = (const float*)d_in[0];
  const int* ei = (const int*)d_in[1];      // [2, NE]: src row then dst row
  const float* eattr = (const float*)d_in[2];

  char* w = (char*)d_ws;
  int* degi      = (int*)w;                 w += NN * 4;
  int* cursor    = (int*)w;                 w += NN * 4;
  int* rowptr    = (int*)w;                 w += (NN + 1) * 4;
  int* csr_eid   = (int*)w;                 w += NE * 4;
  int* csr_src   = (int*)w;                 w += NE * 4;
  float* loop_attr = (float*)w;             w += (size_t)NN * ED * 4;
  float* ea_csr  = (float*)w;               w += (size_t)NE * ED * 4;
  float* xl      = (float*)w;               w += (size_t)NN * HC * 4;
  float* hbuf    = (float*)w;               w += (size_t)NN * CD * 4;

  // graph structure + permuted edge attrs (layer-invariant)
  hipMemsetAsync(degi, 0, NN * 4, stream);
  hipMemsetAsync(cursor, 0, NN * 4, stream);
  k_count<<<(NE + 255) / 256, 256, 0, stream>>>(ei + NE, degi);
  k_scan<<<1, 256, 0, stream>>>(degi, rowptr);
  k_fill<<<(NE + 255) / 256, 256, 0, stream>>>(ei, rowptr, cursor, csr_eid, csr_src);
  k_loopattr<<<(NN + 3) / 4, 256, 0, stream>>>(csr_eid, rowptr, eattr, loop_attr);
  k_eacsr<<<(NE * 4 + 255) / 256, 256, 0, stream>>>(csr_eid, eattr, ea_csr);

  for (int l = 0; l < 3; l++) {
    const float* Wl  = (const float*)d_in[3 + 5 * l];
    const float* bl  = (const float*)d_in[4 + 5 * l];
    const float* We  = (const float*)d_in[5 + 5 * l];
    const float* att = (const float*)d_in[6 + 5 * l];
    const float* b   = (const float*)d_in[7 + 5 * l];

    if (l == 0) k_xl<ND><<<NN / 8, 320, 0, stream>>>(x, Wl, bl, xl);
    else        k_xl<CD><<<NN / 8, 320, 0, stream>>>(hbuf, Wl, bl, xl);

    float* dst_out = (l < 2) ? hbuf : (float*)d_out;
    k_fused<<<NN / 2, 256, 0, stream>>>(csr_src, rowptr, ea_csr, loop_attr,
                                        xl, We, att, b, dst_out);
  }
}